// Round 2
// baseline (1027.868 us; speedup 1.0000x reference)
//
#include <hip/hip_runtime.h>
#include <hip/hip_bf16.h>
#include <hip/hip_fp16.h>

// Problem dims (hard-coded): B=8, S=4096, DIM=1024, M=1024
#define KDIM 1024

typedef __attribute__((ext_vector_type(8))) _Float16  half8;
typedef __attribute__((ext_vector_type(4))) _Float16  half4v;
typedef __attribute__((ext_vector_type(4))) float     f32x4;
typedef __attribute__((ext_vector_type(4))) int       i32x4;

// async global->LDS, 16B per lane. LDS base must be wave-uniform; HW adds lane*16.
__device__ __forceinline__ void g2l16(const void* g, void* l) {
  __builtin_amdgcn_global_load_lds(
      (const __attribute__((address_space(1))) unsigned int*)g,
      (__attribute__((address_space(3))) unsigned int*)l, 16, 0, 0);
}

__device__ __forceinline__ int q8(float v) {
  int r = (int)rintf(v);
  r = r > 127 ? 127 : r;
  r = r < -127 ? -127 : r;
  return r;
}

// ---------------------------------------------------------------------------
// split x (fp32) -> xh fp16, xl8 = i8((x-xh)*2^15), xh8 = i8(x*2^4)
__global__ __launch_bounds__(256) void split_x(
    const float* __restrict__ X, _Float16* __restrict__ Xh,
    char* __restrict__ Xl8, char* __restrict__ Xh8) {
  const int i4 = blockIdx.x * 256 + threadIdx.x;
  const float4 v = ((const float4*)X)[i4];
  float vv[4] = {v.x, v.y, v.z, v.w};
  half4v h;
  int l8 = 0, h8 = 0;
#pragma unroll
  for (int j = 0; j < 4; ++j) {
    _Float16 hh = (_Float16)vv[j];
    h[j] = hh;
    float l = vv[j] - (float)hh;
    l8 |= (q8(l * 32768.f) & 0xff) << (8 * j);
    h8 |= (q8(vv[j] * 16.f) & 0xff) << (8 * j);
  }
  ((half4v*)Xh)[i4] = h;
  ((int*)Xl8)[i4] = l8;
  ((int*)Xh8)[i4] = h8;
}

// W: scales hi8=2^9, lo8=2^20 (|W|<=~0.18). mem: hi8=2^4, lo8=2^15 (|mem|<=~5.2).
__global__ __launch_bounds__(256) void prep_wm(
    const float* __restrict__ W, const float* __restrict__ mem,
    _Float16* __restrict__ Wh, char* __restrict__ Wl8, char* __restrict__ Wh8,
    _Float16* __restrict__ Mh, char* __restrict__ Ml8, char* __restrict__ Mh8) {
  const int i = blockIdx.x * 256 + threadIdx.x;
  float w = W[i];
  _Float16 wh = (_Float16)w;
  Wh[i] = wh;
  Wl8[i] = (char)q8((w - (float)wh) * 1048576.f);
  Wh8[i] = (char)q8(w * 512.f);
  float m = mem[i];
  _Float16 mh = (_Float16)m;
  Mh[i] = mh;
  Ml8[i] = (char)q8((m - (float)mh) * 32768.f);
  Mh8[i] = (char)q8(m * 16.f);
}

// transpose mem [m][d] -> memT fp16 [d][m] (B^T layout for GEMM3)
__global__ __launch_bounds__(256) void transpose_mem(
    const float* __restrict__ mem, _Float16* __restrict__ memT) {
  __shared__ float tl[32][33];
  int bx = blockIdx.x, by = blockIdx.y;
  int tx = threadIdx.x, ty = threadIdx.y;   // (32, 8)
#pragma unroll
  for (int j = 0; j < 4; ++j)
    tl[ty + 8 * j][tx] = mem[(by * 32 + ty + 8 * j) * 1024 + bx * 32 + tx];
  __syncthreads();
#pragma unroll
  for (int j = 0; j < 4; ++j)
    memT[(bx * 32 + ty + 8 * j) * 1024 + by * 32 + tx] =
        (_Float16)tl[tx][ty + 8 * j];
}

// ---------------------------------------------------------------------------
// Compensated GEMM, C = A @ B^T.
//   hh  : fp16 x fp16 MFMA (16x16x32), fp32 acc  — exact fp16 products
//   cross: Al8 x Bh8 + Ah8 x Bl8 via i8 MFMA (16x16x64, 2x rate), shared i32 acc
// logit = accf + accif * combineScale (scales are powers of 2, chosen equal).
// 128x128 tile, BK=64 (16 iterations -> half the barriers of round 1), 4 waves.
// MODE 0: epilogue adds bias, writes q as (fp16 h, i8 lo*2^15, i8 hi*2^4).
// MODE 1: epilogue writes fp32 logits.
template <int MODE>
__global__ __launch_bounds__(256) void gemm_i8(
    const _Float16* __restrict__ Agh, const char* __restrict__ Agl8,
    const char* __restrict__ Agh8,
    const _Float16* __restrict__ Bgh, const char* __restrict__ Bgl8,
    const char* __restrict__ Bgh8,
    const float* __restrict__ bias,
    _Float16* __restrict__ Oh, char* __restrict__ Ol8, char* __restrict__ Oh8,
    float* __restrict__ Of, float combineScale) {
  // 64 KB LDS total (exactly the static limit)
  __shared__ __attribute__((aligned(16))) _Float16 Ah[2][128 * 32];  // 16 KB, khalf-major
  __shared__ __attribute__((aligned(16))) _Float16 Bh[2][128 * 32];  // 16 KB
  __shared__ __attribute__((aligned(16))) char Al8[128 * 64];        // 8 KB
  __shared__ __attribute__((aligned(16))) char Ah8s[128 * 64];       // 8 KB
  __shared__ __attribute__((aligned(16))) char Bl8[128 * 64];        // 8 KB
  __shared__ __attribute__((aligned(16))) char Bh8s[128 * 64];       // 8 KB

  const int t = threadIdx.x;
  const int wave = t >> 6;
  const int lane = t & 63;
  const int wm = wave & 1, wn = wave >> 1;
  const int tileM = blockIdx.y * 128;
  const int tileN = blockIdx.x * 128;

  f32x4 accf[4][4] = {};
  i32x4 acci[4][4] = {};

  const int rs = lane >> 2;         // staging: row within 16-row group
  const int c8 = (lane & 3) * 8;    // fp16 k-elem offset (8 fp16 = 16 B)
  const int c16 = (lane & 3) * 16;  // i8 k-elem offset (16 i8 = 16 B)

  for (int kt = 0; kt < KDIM / 64; ++kt) {
    const int k0 = kt * 64;
    __syncthreads();
#pragma unroll
    for (int g = 0; g < 2; ++g) {
      const int rb = wave * 32 + g * 16;   // wave-uniform LDS row base
      const size_t ga = (size_t)(tileM + rb + rs) * KDIM;
      const size_t gb = (size_t)(tileN + rb + rs) * KDIM;
#pragma unroll
      for (int h = 0; h < 2; ++h) {
        g2l16(Agh + ga + k0 + h * 32 + c8, &Ah[h][rb * 32]);
        g2l16(Bgh + gb + k0 + h * 32 + c8, &Bh[h][rb * 32]);
      }
      g2l16(Agl8 + ga + k0 + c16, &Al8[rb * 64]);
      g2l16(Agh8 + ga + k0 + c16, &Ah8s[rb * 64]);
      g2l16(Bgl8 + gb + k0 + c16, &Bl8[rb * 64]);
      g2l16(Bgh8 + gb + k0 + c16, &Bh8s[rb * 64]);
    }
    __syncthreads();

    const int fr = lane & 15;
    const int fo = (lane >> 4) * 16;  // byte offset within a 64 B LDS row

    // fp16 hh term: 2 khalves x 16 MFMA
#pragma unroll
    for (int h = 0; h < 2; ++h) {
      half8 af[4], bf[4];
#pragma unroll
      for (int mf = 0; mf < 4; ++mf)
        af[mf] = *(const half8*)((const char*)&Ah[h][(wm * 64 + mf * 16 + fr) * 32] + fo);
#pragma unroll
      for (int nf = 0; nf < 4; ++nf)
        bf[nf] = *(const half8*)((const char*)&Bh[h][(wn * 64 + nf * 16 + fr) * 32] + fo);
#pragma unroll
      for (int mf = 0; mf < 4; ++mf)
#pragma unroll
        for (int nf = 0; nf < 4; ++nf)
          accf[mf][nf] = __builtin_amdgcn_mfma_f32_16x16x32_f16(
              af[mf], bf[nf], accf[mf][nf], 0, 0, 0);
    }

    // i8 cross terms: 32 MFMA at K=64 (2x rate)
    {
      i32x4 al[4], a8[4], bl[4], b8[4];
#pragma unroll
      for (int mf = 0; mf < 4; ++mf) {
        const int r = wm * 64 + mf * 16 + fr;
        al[mf] = *(const i32x4*)(&Al8[r * 64 + fo]);
        a8[mf] = *(const i32x4*)(&Ah8s[r * 64 + fo]);
      }
#pragma unroll
      for (int nf = 0; nf < 4; ++nf) {
        const int r = wn * 64 + nf * 16 + fr;
        bl[nf] = *(const i32x4*)(&Bl8[r * 64 + fo]);
        b8[nf] = *(const i32x4*)(&Bh8s[r * 64 + fo]);
      }
#pragma unroll
      for (int mf = 0; mf < 4; ++mf)
#pragma unroll
        for (int nf = 0; nf < 4; ++nf) {
          acci[mf][nf] = __builtin_amdgcn_mfma_i32_16x16x64_i8(
              al[mf], b8[nf], acci[mf][nf], 0, 0, 0);
          acci[mf][nf] = __builtin_amdgcn_mfma_i32_16x16x64_i8(
              a8[mf], bl[nf], acci[mf][nf], 0, 0, 0);
        }
    }
  }

  // epilogue. C/D layout: col = lane&15, row = (lane>>4)*4 + reg
  const int er = (lane >> 4) * 4;
  const int ec = lane & 15;
#pragma unroll
  for (int nf = 0; nf < 4; ++nf) {
    const int col = tileN + wn * 64 + nf * 16 + ec;
    float bv = 0.0f;
    if constexpr (MODE == 0) bv = bias[col];
#pragma unroll
    for (int mf = 0; mf < 4; ++mf) {
#pragma unroll
      for (int r = 0; r < 4; ++r) {
        const int row = tileM + wm * 64 + mf * 16 + er + r;
        float v = accf[mf][nf][r] + (float)acci[mf][nf][r] * combineScale;
        const size_t idx = (size_t)row * KDIM + col;
        if constexpr (MODE == 0) {
          v += bv;
          _Float16 h = (_Float16)v;
          Oh[idx] = h;
          Ol8[idx] = (char)q8((v - (float)h) * 32768.f);
          Oh8[idx] = (char)q8(v * 16.f);
        } else {
          Of[idx] = v;
        }
      }
    }
  }
}

// ---------------------------------------------------------------------------
// softmax over M=1024 per row; attn fp32 in, probs fp16 out. 1 row / block.
__global__ __launch_bounds__(256) void softmax_k(
    const float* __restrict__ attn, _Float16* __restrict__ probs) {
  const int row = blockIdx.x;
  const int t = threadIdx.x;
  const int wave = t >> 6, lane = t & 63;
  __shared__ float redm[4];
  __shared__ float reds[4];

  float4 v = ((const float4*)(attn + (size_t)row * 1024))[t];
  float m = fmaxf(fmaxf(v.x, v.y), fmaxf(v.z, v.w));
#pragma unroll
  for (int off = 32; off; off >>= 1) m = fmaxf(m, __shfl_xor(m, off));
  if (lane == 0) redm[wave] = m;
  __syncthreads();
  m = fmaxf(fmaxf(redm[0], redm[1]), fmaxf(redm[2], redm[3]));

  float e0 = expf(v.x - m), e1 = expf(v.y - m);
  float e2 = expf(v.z - m), e3 = expf(v.w - m);
  float s = e0 + e1 + e2 + e3;
#pragma unroll
  for (int off = 32; off; off >>= 1) s += __shfl_xor(s, off);
  if (lane == 0) reds[wave] = s;
  __syncthreads();
  s = reds[0] + reds[1] + reds[2] + reds[3];
  const float inv = 1.0f / s;

  half4v o;
  o[0] = (_Float16)(e0 * inv);
  o[1] = (_Float16)(e1 * inv);
  o[2] = (_Float16)(e2 * inv);
  o[3] = (_Float16)(e3 * inv);
  ((half4v*)(probs + (size_t)row * 1024))[t] = o;
}

// ---------------------------------------------------------------------------
// GEMM3: context = probs @ memT^T, fp16 single-product MFMA, fp32 out.
__global__ __launch_bounds__(256) void gemm3_kernel(
    const _Float16* __restrict__ Ag, const _Float16* __restrict__ Bg,
    float* __restrict__ Of) {
  __shared__ __attribute__((aligned(16))) _Float16 As[128 * 32];
  __shared__ __attribute__((aligned(16))) _Float16 Bs[128 * 32];

  const int t = threadIdx.x;
  const int wave = t >> 6;
  const int lane = t & 63;
  const int wm = wave & 1, wn = wave >> 1;
  const int tileM = blockIdx.y * 128;
  const int tileN = blockIdx.x * 128;

  f32x4 acc[4][4] = {};
  const int rS = lane >> 2;
  const int cS = (lane & 3) * 8;

  for (int kt = 0; kt < KDIM / 32; ++kt) {
    const int k0 = kt * 32;
    __syncthreads();
#pragma unroll
    for (int i = 0; i < 2; ++i) {
      const int rb = i * 64 + wave * 16;
      g2l16(Ag + (size_t)(tileM + rb + rS) * KDIM + k0 + cS, &As[rb * 32]);
      g2l16(Bg + (size_t)(tileN + rb + rS) * KDIM + k0 + cS, &Bs[rb * 32]);
    }
    __syncthreads();

    const int fr = lane & 15;
    const int fk = (lane >> 4) * 8;
    half8 af[4], bf[4];
#pragma unroll
    for (int mf = 0; mf < 4; ++mf)
      af[mf] = *(const half8*)(&As[(wm * 64 + mf * 16 + fr) * 32 + fk]);
#pragma unroll
    for (int nf = 0; nf < 4; ++nf)
      bf[nf] = *(const half8*)(&Bs[(wn * 64 + nf * 16 + fr) * 32 + fk]);
#pragma unroll
    for (int mf = 0; mf < 4; ++mf)
#pragma unroll
      for (int nf = 0; nf < 4; ++nf)
        acc[mf][nf] = __builtin_amdgcn_mfma_f32_16x16x32_f16(af[mf], bf[nf], acc[mf][nf], 0, 0, 0);
  }

  const int er = (lane >> 4) * 4;
  const int ec = lane & 15;
#pragma unroll
  for (int nf = 0; nf < 4; ++nf) {
    const int col = tileN + wn * 64 + nf * 16 + ec;
#pragma unroll
    for (int mf = 0; mf < 4; ++mf)
#pragma unroll
      for (int r = 0; r < 4; ++r) {
        const int row = tileM + wm * 64 + mf * 16 + er + r;
        Of[(size_t)row * KDIM + col] = acc[mf][nf][r];
      }
  }
}

// ---------------------------------------------------------------------------
extern "C" void kernel_launch(void* const* d_in, const int* in_sizes, int n_in,
                              void* d_out, int out_size, void* d_ws, size_t ws_size,
                              hipStream_t stream) {
  const float* x   = (const float*)d_in[0];   // [32768][1024]
  const float* W   = (const float*)d_in[1];   // [1024][1024]  (out, in) = B^T layout
  const float* b   = (const float*)d_in[2];   // [1024]
  const float* mem = (const float*)d_in[3];   // [1024][1024]  (m, e)    = B^T layout
  float* out = (float*)d_out;

  char* ws = (char*)d_ws;
  const size_t MB = 1024 * 1024;
  _Float16* qh   = (_Float16*)(ws);            // 64 MB
  char*     ql8  = ws + 64 * MB;               // 32 MB
  char*     qh8  = ws + 96 * MB;               // 32 MB
  float*    attn = (float*)(ws + 128 * MB);    // 128 MB (overlays x-splits after gemm1)
  _Float16* xh   = (_Float16*)(ws + 128 * MB); // 64 MB
  char*     xl8  = ws + 192 * MB;              // 32 MB
  char*     xh8  = ws + 224 * MB;              // 32 MB
  _Float16* Wh   = (_Float16*)(ws + 256 * MB); // 2 MB
  char*     Wl8  = ws + 258 * MB;              // 1 MB
  char*     Wh8  = ws + 259 * MB;              // 1 MB
  _Float16* Mh   = (_Float16*)(ws + 260 * MB); // 2 MB
  char*     Ml8  = ws + 262 * MB;              // 1 MB
  char*     Mh8  = ws + 263 * MB;              // 1 MB
  _Float16* memT = (_Float16*)(ws + 264 * MB); // 2 MB
  _Float16* probs = (_Float16*)ws;             // overlays qh (dead after gemm2)

  split_x<<<32768, 256, 0, stream>>>(x, xh, xl8, xh8);
  prep_wm<<<4096, 256, 0, stream>>>(W, mem, Wh, Wl8, Wh8, Mh, Ml8, Mh8);
  transpose_mem<<<dim3(32, 32), dim3(32, 8), 0, stream>>>(mem, memT);

  // q = x @ W^T + b; combine scale 2^-24 (xl8 2^15 * Wh8 2^9 == xh8 2^4 * Wl8 2^20)
  gemm_i8<0><<<dim3(8, 256), 256, 0, stream>>>(
      xh, xl8, xh8, Wh, Wl8, Wh8, b, qh, ql8, qh8, nullptr, 0x1p-24f);

  // attn = q @ mem^T; combine scale 2^-19 (ql8 2^15 * Mh8 2^4 == qh8 2^4 * Ml8 2^15)
  gemm_i8<1><<<dim3(8, 256), 256, 0, stream>>>(
      qh, ql8, qh8, Mh, Ml8, Mh8, nullptr, nullptr, nullptr, nullptr, attn, 0x1p-19f);

  softmax_k<<<32768, 256, 0, stream>>>(attn, probs);

  // context = probs @ mem  (fp16 single product via memT)
  gemm3_kernel<<<dim3(8, 256), 256, 0, stream>>>(probs, memT, out);
}

// Round 3
// 620.656 us; speedup vs baseline: 1.6561x; 1.6561x over previous
//
#include <hip/hip_runtime.h>
#include <hip/hip_bf16.h>
#include <hip/hip_fp16.h>

// Problem dims (hard-coded): B=8, S=4096, DIM=1024, M=1024
// Algebraic restructure: attn = x @ (mem·W)^T + (mem·b); softmax; out = probs @ mem
#define KDIM 1024

typedef __attribute__((ext_vector_type(8))) __bf16    bf16x8;
typedef __attribute__((ext_vector_type(4))) __bf16    bf16x4;
typedef __attribute__((ext_vector_type(8))) _Float16  half8;
typedef __attribute__((ext_vector_type(4))) _Float16  half4v;
typedef __attribute__((ext_vector_type(4))) float     f32x4;

// async global->LDS, 16B per lane. LDS base must be wave-uniform; HW adds lane*16.
__device__ __forceinline__ void g2l16(const void* g, void* l) {
  __builtin_amdgcn_global_load_lds(
      (const __attribute__((address_space(1))) unsigned int*)g,
      (__attribute__((address_space(3))) unsigned int*)l, 16, 0, 0);
}

__device__ __forceinline__ void split2(float v, __bf16& h, __bf16& l) {
  h = (__bf16)v;
  l = (__bf16)(v - (float)h);
}

// ---------------------------------------------------------------------------
// split mem into bf16 hi/lo (row-major [m][e], already B^T/A layout for P-GEMM)
__global__ __launch_bounds__(256) void split_mem(
    const float* __restrict__ mem, __bf16* __restrict__ Mh, __bf16* __restrict__ Ml) {
  int i = blockIdx.x * 256 + threadIdx.x;   // 1M threads
  __bf16 h, l;
  split2(mem[i], h, l);
  Mh[i] = h; Ml[i] = l;
}

// transpose W [e][d] -> Wt [d][e], split to bf16 hi/lo (B^T layout for P-GEMM)
__global__ __launch_bounds__(256) void transpose_split_W(
    const float* __restrict__ W, __bf16* __restrict__ Wth, __bf16* __restrict__ Wtl) {
  __shared__ float tl[32][33];
  int bx = blockIdx.x, by = blockIdx.y;
  int tx = threadIdx.x, ty = threadIdx.y;   // (32, 8)
#pragma unroll
  for (int j = 0; j < 4; ++j)
    tl[ty + 8 * j][tx] = W[(by * 32 + ty + 8 * j) * 1024 + bx * 32 + tx];
  __syncthreads();
#pragma unroll
  for (int j = 0; j < 4; ++j) {
    float v = tl[tx][ty + 8 * j];
    __bf16 h, l;
    split2(v, h, l);
    const int idx = (bx * 32 + ty + 8 * j) * 1024 + by * 32 + tx;
    Wth[idx] = h; Wtl[idx] = l;
  }
}

// transpose mem [m][d] -> memT fp16 [d][m] (B^T layout for GEMM3)
__global__ __launch_bounds__(256) void transpose_mem(
    const float* __restrict__ mem, _Float16* __restrict__ memT) {
  __shared__ float tl[32][33];
  int bx = blockIdx.x, by = blockIdx.y;
  int tx = threadIdx.x, ty = threadIdx.y;   // (32, 8)
#pragma unroll
  for (int j = 0; j < 4; ++j)
    tl[ty + 8 * j][tx] = mem[(by * 32 + ty + 8 * j) * 1024 + bx * 32 + tx];
  __syncthreads();
#pragma unroll
  for (int j = 0; j < 4; ++j)
    memT[(bx * 32 + ty + 8 * j) * 1024 + by * 32 + tx] =
        (_Float16)tl[tx][ty + 8 * j];
}

// c[m] = sum_e b[e] * mem[m][e]  (fp32). One wave per row.
__global__ __launch_bounds__(256) void bias_c(
    const float* __restrict__ b, const float* __restrict__ mem,
    float* __restrict__ c) {
  const int wave = threadIdx.x >> 6, lane = threadIdx.x & 63;
  const int row = blockIdx.x * 4 + wave;
  float s = 0.f;
#pragma unroll
  for (int j = 0; j < 16; ++j) {
    const int e = lane + 64 * j;
    s += b[e] * mem[row * 1024 + e];
  }
#pragma unroll
  for (int off = 32; off; off >>= 1) s += __shfl_xor(s, off);
  if (lane == 0) c[row] = s;
}

// ---------------------------------------------------------------------------
// Split-bf16 compensated GEMM, C = A @ B^T (3 MFMA products: hh + hl + lh).
// Round-1 structure (known-good): 128x128 tile, BK=32, 32 KB LDS, 4 waves.
// MODE 0 (P-GEMM): A pre-split bf16 hi/lo; epilogue writes C as bf16 hi/lo.
// MODE 1 (big GEMM): A = x fp32 (split inline during staging); epilogue adds
//                    bias[col] and writes fp32.
template <int MODE>
__global__ __launch_bounds__(256) void gemm_split(
    const float* __restrict__ X,
    const __bf16* __restrict__ Agh, const __bf16* __restrict__ Agl,
    const __bf16* __restrict__ Bgh, const __bf16* __restrict__ Bgl,
    const float* __restrict__ bias,
    __bf16* __restrict__ Oh, __bf16* __restrict__ Ol,
    float* __restrict__ Of) {
  __shared__ __attribute__((aligned(16))) __bf16 Ah[128 * 32];
  __shared__ __attribute__((aligned(16))) __bf16 Al[128 * 32];
  __shared__ __attribute__((aligned(16))) __bf16 Bh[128 * 32];
  __shared__ __attribute__((aligned(16))) __bf16 Bl[128 * 32];

  const int t = threadIdx.x;
  const int wave = t >> 6;
  const int lane = t & 63;
  const int wm = wave & 1, wn = wave >> 1;
  const int tileM = blockIdx.y * 128;
  const int tileN = blockIdx.x * 128;

  f32x4 acc[4][4] = {};

  const int rS = lane >> 2;        // row within 16-row staging group
  const int cS = (lane & 3) * 8;   // k element offset within BK=32

  for (int kt = 0; kt < KDIM / 32; ++kt) {
    const int k0 = kt * 32;
    __syncthreads();
    // --- stage B^T tile (rows tileN..tileN+127, k0..k0+31), hi+lo
#pragma unroll
    for (int i = 0; i < 2; ++i) {
      const int rb = i * 64 + wave * 16;  // wave-uniform LDS row base
      const int gro = (tileN + rb + rS) * KDIM + k0 + cS;
      g2l16(Bgh + gro, &Bh[rb * 32]);
      g2l16(Bgl + gro, &Bl[rb * 32]);
    }
    if constexpr (MODE == 0) {
#pragma unroll
      for (int i = 0; i < 2; ++i) {
        const int rb = i * 64 + wave * 16;
        const int gro = (tileM + rb + rS) * KDIM + k0 + cS;
        g2l16(Agh + gro, &Ah[rb * 32]);
        g2l16(Agl + gro, &Al[rb * 32]);
      }
    } else {
      // inline fp32 -> bf16 hi/lo split of x during staging
#pragma unroll
      for (int i = 0; i < 4; ++i) {
        const int idx = i * 256 + t;
        const int row = idx >> 3;
        const int c4 = (idx & 7) * 4;
        const float4 v = *(const float4*)(X + (size_t)(tileM + row) * KDIM + k0 + c4);
        float vv[4] = {v.x, v.y, v.z, v.w};
        bf16x4 h, l;
#pragma unroll
        for (int j = 0; j < 4; ++j) {
          __bf16 hh = (__bf16)vv[j];
          h[j] = hh;
          l[j] = (__bf16)(vv[j] - (float)hh);
        }
        *(bf16x4*)(&Ah[row * 32 + c4]) = h;
        *(bf16x4*)(&Al[row * 32 + c4]) = l;
      }
    }
    __syncthreads();

    const int fr = lane & 15;
    const int fk = (lane >> 4) * 8;
    bf16x8 afh[4], afl[4], bfh[4], bfl[4];
#pragma unroll
    for (int mf = 0; mf < 4; ++mf) {
      const int r = wm * 64 + mf * 16 + fr;
      afh[mf] = *(const bf16x8*)(&Ah[r * 32 + fk]);
      afl[mf] = *(const bf16x8*)(&Al[r * 32 + fk]);
    }
#pragma unroll
    for (int nf = 0; nf < 4; ++nf) {
      const int r = wn * 64 + nf * 16 + fr;
      bfh[nf] = *(const bf16x8*)(&Bh[r * 32 + fk]);
      bfl[nf] = *(const bf16x8*)(&Bl[r * 32 + fk]);
    }
#pragma unroll
    for (int mf = 0; mf < 4; ++mf)
#pragma unroll
      for (int nf = 0; nf < 4; ++nf) {
        acc[mf][nf] = __builtin_amdgcn_mfma_f32_16x16x32_bf16(afh[mf], bfh[nf], acc[mf][nf], 0, 0, 0);
        acc[mf][nf] = __builtin_amdgcn_mfma_f32_16x16x32_bf16(afh[mf], bfl[nf], acc[mf][nf], 0, 0, 0);
        acc[mf][nf] = __builtin_amdgcn_mfma_f32_16x16x32_bf16(afl[mf], bfh[nf], acc[mf][nf], 0, 0, 0);
      }
  }

  // --- epilogue. C/D layout: col = lane&15, row = (lane>>4)*4 + reg
  const int er = (lane >> 4) * 4;
  const int ec = lane & 15;
#pragma unroll
  for (int nf = 0; nf < 4; ++nf) {
    const int col = tileN + wn * 64 + nf * 16 + ec;
    float bv = 0.0f;
    if constexpr (MODE == 1) bv = bias[col];
#pragma unroll
    for (int mf = 0; mf < 4; ++mf) {
#pragma unroll
      for (int r = 0; r < 4; ++r) {
        const int row = tileM + wm * 64 + mf * 16 + er + r;
        const size_t idx = (size_t)row * KDIM + col;
        float v = acc[mf][nf][r];
        if constexpr (MODE == 0) {
          __bf16 h = (__bf16)v;
          Oh[idx] = h;
          Ol[idx] = (__bf16)(v - (float)h);
        } else {
          Of[idx] = v + bv;
        }
      }
    }
  }
}

// ---------------------------------------------------------------------------
// softmax over M=1024 per row; attn fp32 in, probs fp16 out. 1 row / block.
__global__ __launch_bounds__(256) void softmax_k(
    const float* __restrict__ attn, _Float16* __restrict__ probs) {
  const int row = blockIdx.x;
  const int t = threadIdx.x;
  const int wave = t >> 6, lane = t & 63;
  __shared__ float redm[4];
  __shared__ float reds[4];

  float4 v = ((const float4*)(attn + (size_t)row * 1024))[t];
  float m = fmaxf(fmaxf(v.x, v.y), fmaxf(v.z, v.w));
#pragma unroll
  for (int off = 32; off; off >>= 1) m = fmaxf(m, __shfl_xor(m, off));
  if (lane == 0) redm[wave] = m;
  __syncthreads();
  m = fmaxf(fmaxf(redm[0], redm[1]), fmaxf(redm[2], redm[3]));

  float e0 = expf(v.x - m), e1 = expf(v.y - m);
  float e2 = expf(v.z - m), e3 = expf(v.w - m);
  float s = e0 + e1 + e2 + e3;
#pragma unroll
  for (int off = 32; off; off >>= 1) s += __shfl_xor(s, off);
  if (lane == 0) reds[wave] = s;
  __syncthreads();
  s = reds[0] + reds[1] + reds[2] + reds[3];
  const float inv = 1.0f / s;

  half4v o;
  o[0] = (_Float16)(e0 * inv);
  o[1] = (_Float16)(e1 * inv);
  o[2] = (_Float16)(e2 * inv);
  o[3] = (_Float16)(e3 * inv);
  ((half4v*)(probs + (size_t)row * 1024))[t] = o;
}

// ---------------------------------------------------------------------------
// GEMM3: context = probs @ memT^T, fp16 single-product MFMA, fp32 out.
__global__ __launch_bounds__(256) void gemm3_kernel(
    const _Float16* __restrict__ Ag, const _Float16* __restrict__ Bg,
    float* __restrict__ Of) {
  __shared__ __attribute__((aligned(16))) _Float16 As[128 * 32];
  __shared__ __attribute__((aligned(16))) _Float16 Bs[128 * 32];

  const int t = threadIdx.x;
  const int wave = t >> 6;
  const int lane = t & 63;
  const int wm = wave & 1, wn = wave >> 1;
  const int tileM = blockIdx.y * 128;
  const int tileN = blockIdx.x * 128;

  f32x4 acc[4][4] = {};
  const int rS = lane >> 2;
  const int cS = (lane & 3) * 8;

  for (int kt = 0; kt < KDIM / 32; ++kt) {
    const int k0 = kt * 32;
    __syncthreads();
#pragma unroll
    for (int i = 0; i < 2; ++i) {
      const int rb = i * 64 + wave * 16;
      g2l16(Ag + (size_t)(tileM + rb + rS) * KDIM + k0 + cS, &As[rb * 32]);
      g2l16(Bg + (size_t)(tileN + rb + rS) * KDIM + k0 + cS, &Bs[rb * 32]);
    }
    __syncthreads();

    const int fr = lane & 15;
    const int fk = (lane >> 4) * 8;
    half8 af[4], bf[4];
#pragma unroll
    for (int mf = 0; mf < 4; ++mf)
      af[mf] = *(const half8*)(&As[(wm * 64 + mf * 16 + fr) * 32 + fk]);
#pragma unroll
    for (int nf = 0; nf < 4; ++nf)
      bf[nf] = *(const half8*)(&Bs[(wn * 64 + nf * 16 + fr) * 32 + fk]);
#pragma unroll
    for (int mf = 0; mf < 4; ++mf)
#pragma unroll
      for (int nf = 0; nf < 4; ++nf)
        acc[mf][nf] = __builtin_amdgcn_mfma_f32_16x16x32_f16(af[mf], bf[nf], acc[mf][nf], 0, 0, 0);
  }

  const int er = (lane >> 4) * 4;
  const int ec = lane & 15;
#pragma unroll
  for (int nf = 0; nf < 4; ++nf) {
    const int col = tileN + wn * 64 + nf * 16 + ec;
#pragma unroll
    for (int mf = 0; mf < 4; ++mf)
#pragma unroll
      for (int r = 0; r < 4; ++r) {
        const int row = tileM + wm * 64 + mf * 16 + er + r;
        Of[(size_t)row * KDIM + col] = acc[mf][nf][r];
      }
  }
}

// ---------------------------------------------------------------------------
extern "C" void kernel_launch(void* const* d_in, const int* in_sizes, int n_in,
                              void* d_out, int out_size, void* d_ws, size_t ws_size,
                              hipStream_t stream) {
  const float* x   = (const float*)d_in[0];   // [32768][1024]
  const float* W   = (const float*)d_in[1];   // [1024][1024]  (out=e, in=d)
  const float* b   = (const float*)d_in[2];   // [1024]
  const float* mem = (const float*)d_in[3];   // [1024][1024]  (m, e)
  float* out = (float*)d_out;

  char* ws = (char*)d_ws;
  const size_t MB = 1024 * 1024;
  float*    attn  = (float*)(ws);              // 128 MB
  _Float16* probs = (_Float16*)(ws + 128 * MB);// 64 MB
  __bf16*   Mh    = (__bf16*)(ws + 192 * MB);  // 2 MB
  __bf16*   Ml    = (__bf16*)(ws + 194 * MB);  // 2 MB
  __bf16*   Wth   = (__bf16*)(ws + 196 * MB);  // 2 MB
  __bf16*   Wtl   = (__bf16*)(ws + 198 * MB);  // 2 MB
  __bf16*   Ph    = (__bf16*)(ws + 200 * MB);  // 2 MB
  __bf16*   Pl    = (__bf16*)(ws + 202 * MB);  // 2 MB
  _Float16* memT  = (_Float16*)(ws + 204 * MB);// 2 MB
  float*    cvec  = (float*)(ws + 206 * MB);   // 4 KB

  // preps (all tiny)
  split_mem<<<4096, 256, 0, stream>>>(mem, Mh, Ml);
  transpose_split_W<<<dim3(32, 32), dim3(32, 8), 0, stream>>>(W, Wth, Wtl);
  transpose_mem<<<dim3(32, 32), dim3(32, 8), 0, stream>>>(mem, memT);
  bias_c<<<256, 256, 0, stream>>>(b, mem, cvec);

  // P = mem @ W  (P[m][d] = sum_e mem[m][e] W[e][d]); split-bf16, out split bf16
  gemm_split<0><<<dim3(8, 8), 256, 0, stream>>>(
      nullptr, Mh, Ml, Wth, Wtl, nullptr, Ph, Pl, nullptr);

  // attn = x @ P^T + c  (split-bf16 via inline x split; fp32 logits)
  gemm_split<1><<<dim3(8, 256), 256, 0, stream>>>(
      x, nullptr, nullptr, Ph, Pl, cvec, nullptr, nullptr, attn);

  softmax_k<<<32768, 256, 0, stream>>>(attn, probs);

  // context = probs @ mem  (fp16 single product via memT)
  gemm3_kernel<<<dim3(8, 256), 256, 0, stream>>>(probs, memT, out);
}